// Round 12
// baseline (665.334 us; speedup 1.0000x reference)
//
#include <hip/hip_runtime.h>

#define E_CNT 200000
#define N_CNT 50000
#define CS_PARTS 128

typedef __attribute__((ext_vector_type(8))) unsigned short ushort8;
typedef __attribute__((ext_vector_type(4))) unsigned short us4;
typedef __attribute__((ext_vector_type(4))) float f32x4;
typedef __bf16 bf16x8 __attribute__((ext_vector_type(8)));

static __device__ __forceinline__ unsigned short f2bf(float f) {
  unsigned int u = __builtin_bit_cast(unsigned int, f);
  u += 0x7FFFu + ((u >> 16) & 1u);
  return (unsigned short)(u >> 16);
}
static __device__ __forceinline__ float bf2f(unsigned short u) {
  unsigned int x = ((unsigned int)u) << 16;
  return __builtin_bit_cast(float, x);
}

// ---------- fused weight prep ----------
// blocks 0..159: 5 subs x 32 blocks of frag-ready bf16 W conversion
//   sub0: We_e -> BpEe   sub1: We_s -> BpPs   sub2: We_r -> BpPr
//   sub3: Wn_e -> BpNe   sub4: Wn_v -> BpPn
// blocks 160/161: ce = be + g@We_g ; cn = bn + g@Wn_g
__global__ void prep_all(const float* __restrict__ We, const float* __restrict__ be,
                         const float* __restrict__ Wn, const float* __restrict__ bn,
                         const float* __restrict__ g, unsigned short* __restrict__ BpEe,
                         unsigned short* __restrict__ BpPs, unsigned short* __restrict__ BpPr,
                         unsigned short* __restrict__ BpNe, unsigned short* __restrict__ BpPn,
                         float* __restrict__ ce, float* __restrict__ cn) {
  int bid = blockIdx.x;
  if (bid >= 160) {
    int j = threadIdx.x;  // 256
    if (bid == 160) {
      float s = be[j];
      for (int k = 0; k < 128; ++k) s += g[k] * We[(size_t)(768 + k) * 256 + j];
      ce[j] = s;
    } else {
      float s = bn[j];
      for (int k = 0; k < 128; ++k) s += g[k] * Wn[(size_t)(512 + k) * 256 + j];
      cn[j] = s;
    }
    return;
  }
  int sub = bid >> 5;
  const float* W;
  unsigned short* Bp;
  if (sub == 0)      { W = We;           Bp = BpEe; }
  else if (sub == 1) { W = We + 65536;   Bp = BpPs; }
  else if (sub == 2) { W = We + 131072;  Bp = BpPr; }
  else if (sub == 3) { W = Wn;           Bp = BpNe; }
  else               { W = Wn + 65536;   Bp = BpPn; }
  int idx = (bid & 31) * 256 + threadIdx.x;  // 0..8191 (KC=8)
  int lane = idx & 63;
  int t = idx >> 6;
  int F = t & 15;
  int kc = t >> 4;
  int col = F * 16 + (lane & 15);
  int kb = kc * 32 + (lane >> 4) * 8;
  ushort8 v;
#pragma unroll
  for (int j = 0; j < 8; ++j) v[j] = f2bf(W[(size_t)(kb + j) * 256 + col]);
  *reinterpret_cast<ushort8*>(Bp + (size_t)idx * 8) = v;
}

// ---------- CSR permutation build (receiver-sorted edge order) ----------
__global__ void hist(const int* __restrict__ recv, int* __restrict__ count) {
  int e = blockIdx.x * blockDim.x + threadIdx.x;
  if (e < E_CNT) atomicAdd(&count[recv[e]], 1);
}

__global__ __launch_bounds__(1024) void scan_build(const int* __restrict__ count,
                                                   int* __restrict__ cursor) {
  __shared__ int part[1024];
  const int t = threadIdx.x;
  const int CH = 49;  // 1024*49 >= 50000
  const int base = t * CH;
  int s = 0;
  for (int i = 0; i < CH; ++i) {
    int idx = base + i;
    if (idx < N_CNT) s += count[idx];
  }
  part[t] = s;
  __syncthreads();
  for (int d = 1; d < 1024; d <<= 1) {
    int v = (t >= d) ? part[t - d] : 0;
    __syncthreads();
    part[t] += v;
    __syncthreads();
  }
  int run = (t == 0) ? 0 : part[t - 1];
  for (int i = 0; i < CH; ++i) {
    int idx = base + i;
    if (idx < N_CNT) {
      cursor[idx] = run;
      run += count[idx];
    }
  }
}

__global__ void scatter(const int* __restrict__ recv, const int* __restrict__ snd,
                        int* __restrict__ cursor, int* __restrict__ eord,
                        int* __restrict__ sndS, int* __restrict__ rcvS) {
  int e = blockIdx.x * blockDim.x + threadIdx.x;
  if (e < E_CNT) {
    int r = recv[e];
    int pos = atomicAdd(&cursor[r], 1);
    eord[pos] = e;
    rcvS[pos] = r;
    sndS[pos] = snd[e];
  }
}

// ---------- unified GEMM core: 64-row x 256-col tile, 8 waves, wave 32x64 ----------
// All modes K=256 (NSTEPS=4). acc 32 regs; B loaded per-kk; target <=64 unified
// regs -> 8 waves/SIMD (R11 measured 82% occupancy).
// MODE 0 (PROJ): grid = 3 thirds -> Ps=nodes@We_s, Pr=nodes@We_r, Pn=nodes@Wn_v
//                bf16 slot layout: slot = wn*64 + lr*4 + fn (no bias/relu)
// MODE 1 (EDGE): A = edges[eord[.]] (receiver-sorted); v = relu(acc + ce +
//                Ps[sndS] + Pr[rcvS]); nt-store out0[eord]; f32 atomicAdd into
//                agg[rcvS] (sorted -> L2-local); fused colsum -> partE
// MODE 2 (NODE): A = agg f32; v = relu(acc + cn + Pn[row]); store out1;
//                fused colsum -> partN
template <int MODE>
__global__ __launch_bounds__(512, 8) void gemm_core(
    const float* __restrict__ A0, const unsigned short* __restrict__ Bp0,
    const unsigned short* __restrict__ Bp1, const unsigned short* __restrict__ Bp2,
    const unsigned short* __restrict__ P1, const unsigned short* __restrict__ P2,
    const float* __restrict__ cvec, const int* __restrict__ eord,
    const int* __restrict__ sndS, const int* __restrict__ rcvS,
    float* __restrict__ outF, unsigned short* __restrict__ outP0,
    unsigned short* __restrict__ outP1, unsigned short* __restrict__ outP2,
    float* __restrict__ agg, float* __restrict__ part, int nbThird, int M) {
  __shared__ unsigned short lds[2][64 * 64];  // 2 x 8KB bf16 A tiles, XOR-swizzled

  int bid = blockIdx.x;
  const unsigned short* BpL = Bp0;
  unsigned short* outPL = outP0;
  if (MODE == 0) {
    if (bid >= 2 * nbThird) {
      BpL = Bp2; outPL = outP2; bid -= 2 * nbThird;
    } else if (bid >= nbThird) {
      BpL = Bp1; outPL = outP1; bid -= nbThird;
    }
  }

  const int tid = threadIdx.x;
  const int lane = tid & 63;
  const int wave = tid >> 6;  // 0..7
  const int wm = wave >> 2;   // 0..1 : 32-row half
  const int wn = wave & 3;    // 0..3 : 64-col quarter
  const int q = lane >> 4;    // 0..3
  const int lr = lane & 15;
  const int row0 = bid * 64;

  // staging: thread stages 8 consecutive floats (32B) of one row per K-step
  const int sr = tid >> 3;  // 0..63 row within tile
  const int sc = tid & 7;   // 8-float chunk
  int er = row0 + sr;
  if (er > M - 1) er = M - 1;
  int srow = er;
  if (MODE == 1) srow = eord[er];
  const float* sbase = A0 + (size_t)srow * 256;

  const int swz = sr & 7;
  const int wbase = sr * 64;
  const int s0 = (sc ^ swz) * 8;

  f32x4 acc[2][4] = {};

  // ---- prologue: stage step 0 ----
  {
    const float4* p4 = reinterpret_cast<const float4*>(sbase + sc * 8);
    float fv[8];
    *reinterpret_cast<float4*>(&fv[0]) = p4[0];
    *reinterpret_cast<float4*>(&fv[4]) = p4[1];
    ushort8 w0;
#pragma unroll
    for (int j = 0; j < 8; ++j) w0[j] = f2bf(fv[j]);
    *reinterpret_cast<ushort8*>(&lds[0][wbase + s0]) = w0;
  }
  __syncthreads();

#pragma unroll
  for (int ks = 0; ks < 4; ++ks) {
    const int cc = ks & 1;

    // next-step A loads to regs (issue first: longest latency)
    float4 nf0, nf1;
    if (ks + 1 < 4) {
      const float4* p4 =
          reinterpret_cast<const float4*>(sbase + (ks + 1) * 64 + sc * 8);
      nf0 = p4[0];
      nf1 = p4[1];
    }

    // MFMA on lds[cc]; B-frags loaded per kk-half (16 live B regs)
#pragma unroll
    for (int kk = 0; kk < 2; ++kk) {
      const int kc32 = ks * 2 + kk;
      bf16x8 bfr[4];
#pragma unroll
      for (int fn = 0; fn < 4; ++fn) {
        const int F = wn * 4 + fn;
        bfr[fn] = __builtin_bit_cast(
            bf16x8, *reinterpret_cast<const ushort8*>(
                        BpL + ((size_t)(kc32 * 16 + F) * 64 + lane) * 8));
      }
      bf16x8 a[2];
#pragma unroll
      for (int fm = 0; fm < 2; ++fm) {
        int r = wm * 32 + fm * 16 + lr;
        int slot = (kk * 4 + q) ^ (r & 7);
        a[fm] = __builtin_bit_cast(
            bf16x8, *reinterpret_cast<const ushort8*>(&lds[cc][r * 64 + slot * 8]));
      }
#pragma unroll
      for (int fm = 0; fm < 2; ++fm)
#pragma unroll
        for (int fn = 0; fn < 4; ++fn)
          acc[fm][fn] = __builtin_amdgcn_mfma_f32_16x16x32_bf16(
              a[fm], bfr[fn], acc[fm][fn], 0, 0, 0);
    }

    // convert + write next tile
    if (ks + 1 < 4) {
      float fv[8];
      *reinterpret_cast<float4*>(&fv[0]) = nf0;
      *reinterpret_cast<float4*>(&fv[4]) = nf1;
      ushort8 w0;
#pragma unroll
      for (int j = 0; j < 8; ++j) w0[j] = f2bf(fv[j]);
      *reinterpret_cast<ushort8*>(&lds[cc ^ 1][wbase + s0]) = w0;
      __syncthreads();
    }
  }

  // ---- epilogue ----
  // D mapping: col = lane&15 (=lr), row = q*4 + i
  float bcol[4];
  if (MODE != 0) {
#pragma unroll
    for (int fn = 0; fn < 4; ++fn) bcol[fn] = cvec[wn * 64 + fn * 16 + lr];
  }
  float cs[4] = {0.f, 0.f, 0.f, 0.f};  // per-thread column partials

#pragma unroll
  for (int fm = 0; fm < 2; ++fm) {
    int rb = row0 + wm * 32 + fm * 16 + q * 4;
#pragma unroll
    for (int i = 0; i < 4; ++i) {
      int gr = rb + i;
      if (gr < M) {
        if (MODE == 0) {
          us4 pv;
#pragma unroll
          for (int fn = 0; fn < 4; ++fn) pv[fn] = f2bf(acc[fm][fn][i]);
          *reinterpret_cast<us4*>(outPL + (size_t)gr * 256 + wn * 64 + lr * 4) = pv;
        } else if (MODE == 1) {
          int e = eord[gr];
          int snd = sndS[gr], rcv = rcvS[gr];
          us4 ps = *reinterpret_cast<const us4*>(P1 + (size_t)snd * 256 + wn * 64 + lr * 4);
          us4 pr = *reinterpret_cast<const us4*>(P2 + (size_t)rcv * 256 + wn * 64 + lr * 4);
#pragma unroll
          for (int fn = 0; fn < 4; ++fn) {
            int col = wn * 64 + fn * 16 + lr;
            float v = fmaxf(acc[fm][fn][i] + bcol[fn] + bf2f(ps[fn]) + bf2f(pr[fn]), 0.0f);
            cs[fn] += v;
            __builtin_nontemporal_store(v, &outF[(size_t)e * 256 + col]);
            atomicAdd(agg + (size_t)rcv * 256 + col, v);
          }
        } else {
          us4 pn = *reinterpret_cast<const us4*>(P1 + (size_t)gr * 256 + wn * 64 + lr * 4);
#pragma unroll
          for (int fn = 0; fn < 4; ++fn) {
            int col = wn * 64 + fn * 16 + lr;
            float v = fmaxf(acc[fm][fn][i] + bcol[fn] + bf2f(pn[fn]), 0.0f);
            cs[fn] += v;
            outF[(size_t)gr * 256 + col] = v;
          }
        }
      }
    }
  }

  // ---- fused column sum (MODE 1/2): LDS reduce -> 128 partial slots ----
  if (MODE != 0) {
    float* csum = reinterpret_cast<float*>(&lds[0][0]);  // 1KB, lds is dead
    __syncthreads();
    if (tid < 256) csum[tid] = 0.f;
    __syncthreads();
#pragma unroll
    for (int fn = 0; fn < 4; ++fn) atomicAdd(&csum[wn * 64 + fn * 16 + lr], cs[fn]);
    __syncthreads();
    if (tid < 256)
      atomicAdd(&part[(size_t)(blockIdx.x & (CS_PARTS - 1)) * 256 + tid], csum[tid]);
  }
}

// sum the CS_PARTS partials
__global__ void colsum_p2(const float* __restrict__ part, float* __restrict__ out) {
  const int c = threadIdx.x;  // 256
  float s = 0.f;
  for (int p = 0; p < CS_PARTS; ++p) s += part[(size_t)p * 256 + c];
  out[c] = s;
}

// new_globals = relu([esum | nsum | globals] @ Wg + bg), fp32
__global__ void global_mlp(const float* __restrict__ esum, const float* __restrict__ nsum,
                           const float* __restrict__ gl, const float* __restrict__ Wg,
                           const float* __restrict__ bg, float* __restrict__ out2) {
  __shared__ float red[512];
  int g = threadIdx.x & 127;
  int kg = threadIdx.x >> 7;
  float acc = 0.f;
  for (int k = kg; k < 640; k += 4) {
    float x = (k < 256) ? esum[k] : (k < 512 ? nsum[k - 256] : gl[k - 512]);
    acc += x * Wg[(size_t)k * 128 + g];
  }
  red[threadIdx.x] = acc;
  __syncthreads();
  if (kg == 0) {
    float r = red[g] + red[128 + g] + red[256 + g] + red[384 + g] + bg[g];
    out2[g] = fmaxf(r, 0.f);
  }
}

extern "C" void kernel_launch(void* const* d_in, const int* in_sizes, int n_in,
                              void* d_out, int out_size, void* d_ws, size_t ws_size,
                              hipStream_t stream) {
  const float* nodes = (const float*)d_in[0];
  const float* edges = (const float*)d_in[1];
  const float* gl = (const float*)d_in[2];
  const int* senders = (const int*)d_in[3];
  const int* receivers = (const int*)d_in[4];
  const float* We = (const float*)d_in[5];
  const float* be = (const float*)d_in[6];
  const float* Wn = (const float*)d_in[7];
  const float* bn = (const float*)d_in[8];
  const float* Wg = (const float*)d_in[9];
  const float* bg = (const float*)d_in[10];

  float* out0 = (float*)d_out;               // new_edges [200000,256]
  float* out1 = out0 + (size_t)E_CNT * 256;  // new_nodes [50000,256]
  float* out2 = out1 + (size_t)N_CNT * 256;  // new_globals [128]

  // agg (f32) lives in out1's slot during the edge phase; the node kernel
  // reads agg[row] and overwrites out1[row] for the same rows only.
  float* agg = out1;

  char* ws = (char*)d_ws;
  size_t o = 0;
  int* count = (int*)(ws + o);                      o += 200704;
  float* partE = (float*)(ws + o);                  o += CS_PARTS * 256 * 4;
  float* partN = (float*)(ws + o);                  o += CS_PARTS * 256 * 4;
  size_t zeroBytes = o;  // count + partE + partN zeroed in one memset
  int* cursor = (int*)(ws + o);                     o += 200704;
  int* eord = (int*)(ws + o);                       o += 800000;
  int* sndS = (int*)(ws + o);                       o += 800000;
  int* rcvS = (int*)(ws + o);                       o += 800000;
  unsigned short* Ps = (unsigned short*)(ws + o);   o += (size_t)N_CNT * 256 * 2;  // 25.6MB
  unsigned short* Pr = (unsigned short*)(ws + o);   o += (size_t)N_CNT * 256 * 2;  // 25.6MB
  unsigned short* Pn = (unsigned short*)(ws + o);   o += (size_t)N_CNT * 256 * 2;  // 25.6MB
  unsigned short* BpEe = (unsigned short*)(ws + o); o += 131072;
  unsigned short* BpPs = (unsigned short*)(ws + o); o += 131072;
  unsigned short* BpPr = (unsigned short*)(ws + o); o += 131072;
  unsigned short* BpNe = (unsigned short*)(ws + o); o += 131072;
  unsigned short* BpPn = (unsigned short*)(ws + o); o += 131072;
  float* ce = (float*)(ws + o);                     o += 1024;
  float* cn = (float*)(ws + o);                     o += 1024;
  float* esum = (float*)(ws + o);                   o += 1024;
  float* nsum = (float*)(ws + o);                   o += 1024;

  hipMemsetAsync(ws, 0, zeroBytes, stream);
  hipMemsetAsync(agg, 0, (size_t)N_CNT * 256 * 4, stream);

  prep_all<<<162, 256, 0, stream>>>(We, be, Wn, bn, gl, BpEe, BpPs, BpPr, BpNe,
                                    BpPn, ce, cn);

  hist<<<(E_CNT + 255) / 256, 256, 0, stream>>>(receivers, count);
  scan_build<<<1, 1024, 0, stream>>>(count, cursor);
  scatter<<<(E_CNT + 255) / 256, 256, 0, stream>>>(receivers, senders, cursor,
                                                   eord, sndS, rcvS);

  // three projections in one dispatch: Ps, Pr, Pn (bf16 slot layout)
  const int nbN = (N_CNT + 63) / 64;  // 782
  gemm_core<0><<<3 * nbN, 512, 0, stream>>>(
      nodes, BpPs, BpPr, BpPn, nullptr, nullptr, nullptr, nullptr, nullptr,
      nullptr, nullptr, Ps, Pr, Pn, nullptr, nullptr, nbN, N_CNT);

  // edge (receiver-sorted): relu(edges@We_e + Ps[s] + Pr[r] + ce);
  // nt-store out0[eord]; sorted f32 atomics into agg; fused esum partials
  gemm_core<1><<<E_CNT / 64, 512, 0, stream>>>(
      edges, BpEe, nullptr, nullptr, Ps, Pr, ce, eord, sndS, rcvS, out0,
      nullptr, nullptr, nullptr, agg, partE, 0, E_CNT);

  colsum_p2<<<1, 256, 0, stream>>>(partE, esum);  // == colsum(new_edges)

  // node: relu(agg@Wn_e + Pn[n] + cn), K=256; fused nsum partials
  gemm_core<2><<<nbN, 512, 0, stream>>>(
      agg, BpNe, nullptr, nullptr, Pn, nullptr, cn, nullptr, nullptr, nullptr,
      out1, nullptr, nullptr, nullptr, nullptr, partN, 0, N_CNT);

  colsum_p2<<<1, 256, 0, stream>>>(partN, nsum);

  global_mlp<<<1, 512, 0, stream>>>(esum, nsum, gl, Wg, bg, out2);
}

// Round 13
// 631.565 us; speedup vs baseline: 1.0535x; 1.0535x over previous
//
#include <hip/hip_runtime.h>

#define E_CNT 200000
#define N_CNT 50000
#define CS_PARTS 128

typedef __attribute__((ext_vector_type(8))) unsigned short ushort8;
typedef __attribute__((ext_vector_type(4))) unsigned short us4;
typedef __attribute__((ext_vector_type(4))) float f32x4;
typedef __bf16 bf16x8 __attribute__((ext_vector_type(8)));

static __device__ __forceinline__ unsigned short f2bf(float f) {
  unsigned int u = __builtin_bit_cast(unsigned int, f);
  u += 0x7FFFu + ((u >> 16) & 1u);
  return (unsigned short)(u >> 16);
}
static __device__ __forceinline__ float bf2f(unsigned short u) {
  unsigned int x = ((unsigned int)u) << 16;
  return __builtin_bit_cast(float, x);
}

// ---------- fused weight prep ----------
// blocks 0..159: 5 subs x 32 blocks of frag-ready bf16 W conversion
// blocks 160/161: ce = be + g@We_g ; cn = bn + g@Wn_g
__global__ void prep_all(const float* __restrict__ We, const float* __restrict__ be,
                         const float* __restrict__ Wn, const float* __restrict__ bn,
                         const float* __restrict__ g, unsigned short* __restrict__ BpEe,
                         unsigned short* __restrict__ BpPs, unsigned short* __restrict__ BpPr,
                         unsigned short* __restrict__ BpNe, unsigned short* __restrict__ BpPn,
                         float* __restrict__ ce, float* __restrict__ cn) {
  int bid = blockIdx.x;
  if (bid >= 160) {
    int j = threadIdx.x;  // 256
    if (bid == 160) {
      float s = be[j];
      for (int k = 0; k < 128; ++k) s += g[k] * We[(size_t)(768 + k) * 256 + j];
      ce[j] = s;
    } else {
      float s = bn[j];
      for (int k = 0; k < 128; ++k) s += g[k] * Wn[(size_t)(512 + k) * 256 + j];
      cn[j] = s;
    }
    return;
  }
  int sub = bid >> 5;
  const float* W;
  unsigned short* Bp;
  if (sub == 0)      { W = We;           Bp = BpEe; }
  else if (sub == 1) { W = We + 65536;   Bp = BpPs; }
  else if (sub == 2) { W = We + 131072;  Bp = BpPr; }
  else if (sub == 3) { W = Wn;           Bp = BpNe; }
  else               { W = Wn + 65536;   Bp = BpPn; }
  int idx = (bid & 31) * 256 + threadIdx.x;  // 0..8191 (KC=8)
  int lane = idx & 63;
  int t = idx >> 6;
  int F = t & 15;
  int kc = t >> 4;
  int col = F * 16 + (lane & 15);
  int kb = kc * 32 + (lane >> 4) * 8;
  ushort8 v;
#pragma unroll
  for (int j = 0; j < 8; ++j) v[j] = f2bf(W[(size_t)(kb + j) * 256 + col]);
  *reinterpret_cast<ushort8*>(Bp + (size_t)idx * 8) = v;
}

// ---------- CSR build ----------
__global__ void hist(const int* __restrict__ recv, int* __restrict__ count) {
  int e = blockIdx.x * blockDim.x + threadIdx.x;
  if (e < E_CNT) atomicAdd(&count[recv[e]], 1);
}

__global__ __launch_bounds__(1024) void scan_build(const int* __restrict__ count,
                                                   int* __restrict__ offs,
                                                   int* __restrict__ cursor) {
  __shared__ int part[1024];
  const int t = threadIdx.x;
  const int CH = 49;  // 1024*49 >= 50000
  const int base = t * CH;
  int s = 0;
  for (int i = 0; i < CH; ++i) {
    int idx = base + i;
    if (idx < N_CNT) s += count[idx];
  }
  part[t] = s;
  __syncthreads();
  for (int d = 1; d < 1024; d <<= 1) {
    int v = (t >= d) ? part[t - d] : 0;
    __syncthreads();
    part[t] += v;
    __syncthreads();
  }
  int run = (t == 0) ? 0 : part[t - 1];
  for (int i = 0; i < CH; ++i) {
    int idx = base + i;
    if (idx < N_CNT) {
      offs[idx] = run;
      cursor[idx] = run;
      run += count[idx];
    }
  }
  if (t == 1023) offs[N_CNT] = run;  // == E_CNT
}

__global__ void scatter(const int* __restrict__ recv, int* __restrict__ cursor,
                        int* __restrict__ eord) {
  int e = blockIdx.x * blockDim.x + threadIdx.x;
  if (e < E_CNT) {
    int pos = atomicAdd(&cursor[recv[e]], 1);
    eord[pos] = e;
  }
}

// ---------- unified GEMM core: 64-row x 256-col tile, 8 waves, wave 32x64 ----------
// All modes K=256. acc 32 regs; B per-kk -> <=64 unified regs, 8 waves/SIMD
// (R11/R12 measured 82% occupancy).
// MODE 0 (PROJ): grid thirds -> Ps=nodes@We_s, Pr=nodes@We_r, Pn=nodes@Wn_v
//                bf16 slot layout: slot = wn*64 + lr*4 + fn
// MODE 1 (EDGE): A = edges (natural order); v = relu(acc + ce + Ps[senders] +
//                Pr[receivers]); nt-store out0; fused colsum -> part. NO atomics.
// MODE 2 (NODE): A row n = sum_{j in [offs[n],offs[n+1])} out0[eord[j]]
//                (CSR gather-sum in staging, f32 -> bf16);
//                v = relu(acc + cn + Pn[row]); store out1; fused colsum -> part
template <int MODE>
__global__ __launch_bounds__(512, 8) void gemm_core(
    const float* __restrict__ A0, const unsigned short* __restrict__ Bp0,
    const unsigned short* __restrict__ Bp1, const unsigned short* __restrict__ Bp2,
    const unsigned short* __restrict__ P1, const unsigned short* __restrict__ P2,
    const float* __restrict__ cvec, const int* __restrict__ senders,
    const int* __restrict__ receivers, const int* __restrict__ offs,
    const int* __restrict__ eord, float* __restrict__ outF,
    unsigned short* __restrict__ outP0, unsigned short* __restrict__ outP1,
    unsigned short* __restrict__ outP2, float* __restrict__ part,
    int nbThird, int M) {
  __shared__ unsigned short lds[2][64 * 64];  // 2 x 8KB bf16 A tiles, XOR-swizzled

  int bid = blockIdx.x;
  const unsigned short* BpL = Bp0;
  unsigned short* outPL = outP0;
  if (MODE == 0) {
    if (bid >= 2 * nbThird) {
      BpL = Bp2; outPL = outP2; bid -= 2 * nbThird;
    } else if (bid >= nbThird) {
      BpL = Bp1; outPL = outP1; bid -= nbThird;
    }
  }

  const int tid = threadIdx.x;
  const int lane = tid & 63;
  const int wave = tid >> 6;  // 0..7
  const int wm = wave >> 2;   // 0..1 : 32-row half
  const int wn = wave & 3;    // 0..3 : 64-col quarter
  const int q = lane >> 4;    // 0..3
  const int lr = lane & 15;
  const int row0 = bid * 64;

  // staging: thread stages 8 consecutive floats (32B) of one row per K-step
  const int sr = tid >> 3;  // 0..63 row within tile
  const int sc = tid & 7;   // 8-float chunk
  int er = row0 + sr;
  if (er > M - 1) er = M - 1;
  const float* sbase = A0 + (size_t)er * 256;
  int o0 = 0, o1 = 0;
  if (MODE == 2) {
    o0 = offs[er];
    o1 = offs[er + 1];
  }

  const int swz = sr & 7;
  const int wbase = sr * 64;
  const int s0 = (sc ^ swz) * 8;

  // gather-sum one K-step's 8 floats of the agg row (MODE 2)
  auto gather8 = [&](int ks, f32x4& f0, f32x4& f1) {
    f0 = f32x4{0.f, 0.f, 0.f, 0.f};
    f1 = f32x4{0.f, 0.f, 0.f, 0.f};
    for (int j = o0; j < o1; ++j) {
      const float* p = A0 + (size_t)eord[j] * 256 + ks * 64 + sc * 8;
      f0 += *reinterpret_cast<const f32x4*>(p);
      f1 += *reinterpret_cast<const f32x4*>(p + 4);
    }
  };

  f32x4 acc[2][4] = {};

  // ---- prologue: stage step 0 ----
  {
    f32x4 f0, f1;
    if (MODE == 2) {
      gather8(0, f0, f1);
    } else {
      f0 = *reinterpret_cast<const f32x4*>(sbase + sc * 8);
      f1 = *reinterpret_cast<const f32x4*>(sbase + sc * 8 + 4);
    }
    ushort8 w0;
#pragma unroll
    for (int j = 0; j < 4; ++j) {
      w0[j] = f2bf(f0[j]);
      w0[4 + j] = f2bf(f1[j]);
    }
    *reinterpret_cast<ushort8*>(&lds[0][wbase + s0]) = w0;
  }
  __syncthreads();

#pragma unroll
  for (int ks = 0; ks < 4; ++ks) {
    const int cc = ks & 1;

    // next-step A to regs (issue first: longest latency)
    f32x4 nf0, nf1;
    if (ks + 1 < 4) {
      if (MODE == 2) {
        gather8(ks + 1, nf0, nf1);
      } else {
        nf0 = *reinterpret_cast<const f32x4*>(sbase + (ks + 1) * 64 + sc * 8);
        nf1 = *reinterpret_cast<const f32x4*>(sbase + (ks + 1) * 64 + sc * 8 + 4);
      }
    }

    // MFMA on lds[cc]; B-frags loaded per kk-half
#pragma unroll
    for (int kk = 0; kk < 2; ++kk) {
      const int kc32 = ks * 2 + kk;
      bf16x8 bfr[4];
#pragma unroll
      for (int fn = 0; fn < 4; ++fn) {
        const int F = wn * 4 + fn;
        bfr[fn] = __builtin_bit_cast(
            bf16x8, *reinterpret_cast<const ushort8*>(
                        BpL + ((size_t)(kc32 * 16 + F) * 64 + lane) * 8));
      }
      bf16x8 a[2];
#pragma unroll
      for (int fm = 0; fm < 2; ++fm) {
        int r = wm * 32 + fm * 16 + lr;
        int slot = (kk * 4 + q) ^ (r & 7);
        a[fm] = __builtin_bit_cast(
            bf16x8, *reinterpret_cast<const ushort8*>(&lds[cc][r * 64 + slot * 8]));
      }
#pragma unroll
      for (int fm = 0; fm < 2; ++fm)
#pragma unroll
        for (int fn = 0; fn < 4; ++fn)
          acc[fm][fn] = __builtin_amdgcn_mfma_f32_16x16x32_bf16(
              a[fm], bfr[fn], acc[fm][fn], 0, 0, 0);
    }

    // convert + write next tile
    if (ks + 1 < 4) {
      ushort8 w0;
#pragma unroll
      for (int j = 0; j < 4; ++j) {
        w0[j] = f2bf(nf0[j]);
        w0[4 + j] = f2bf(nf1[j]);
      }
      *reinterpret_cast<ushort8*>(&lds[cc ^ 1][wbase + s0]) = w0;
      __syncthreads();
    }
  }

  // ---- epilogue ----
  // D mapping: col = lane&15 (=lr), row = q*4 + i
  float bcol[4];
  if (MODE != 0) {
#pragma unroll
    for (int fn = 0; fn < 4; ++fn) bcol[fn] = cvec[wn * 64 + fn * 16 + lr];
  }
  float cs[4] = {0.f, 0.f, 0.f, 0.f};  // per-thread column partials

#pragma unroll
  for (int fm = 0; fm < 2; ++fm) {
    int rb = row0 + wm * 32 + fm * 16 + q * 4;
#pragma unroll
    for (int i = 0; i < 4; ++i) {
      int gr = rb + i;
      if (gr < M) {
        if (MODE == 0) {
          us4 pv;
#pragma unroll
          for (int fn = 0; fn < 4; ++fn) pv[fn] = f2bf(acc[fm][fn][i]);
          *reinterpret_cast<us4*>(outPL + (size_t)gr * 256 + wn * 64 + lr * 4) = pv;
        } else if (MODE == 1) {
          int snd = senders[gr], rcv = receivers[gr];
          us4 ps = *reinterpret_cast<const us4*>(P1 + (size_t)snd * 256 + wn * 64 + lr * 4);
          us4 pr = *reinterpret_cast<const us4*>(P2 + (size_t)rcv * 256 + wn * 64 + lr * 4);
#pragma unroll
          for (int fn = 0; fn < 4; ++fn) {
            int col = wn * 64 + fn * 16 + lr;
            float v = fmaxf(acc[fm][fn][i] + bcol[fn] + bf2f(ps[fn]) + bf2f(pr[fn]), 0.0f);
            cs[fn] += v;
            __builtin_nontemporal_store(v, &outF[(size_t)gr * 256 + col]);
          }
        } else {
          us4 pn = *reinterpret_cast<const us4*>(P1 + (size_t)gr * 256 + wn * 64 + lr * 4);
#pragma unroll
          for (int fn = 0; fn < 4; ++fn) {
            int col = wn * 64 + fn * 16 + lr;
            float v = fmaxf(acc[fm][fn][i] + bcol[fn] + bf2f(pn[fn]), 0.0f);
            cs[fn] += v;
            outF[(size_t)gr * 256 + col] = v;
          }
        }
      }
    }
  }

  // ---- fused column sum (MODE 1/2): LDS reduce -> 128 partial slots ----
  if (MODE != 0) {
    float* csum = reinterpret_cast<float*>(&lds[0][0]);  // 1KB, lds is dead
    __syncthreads();
    if (tid < 256) csum[tid] = 0.f;
    __syncthreads();
#pragma unroll
    for (int fn = 0; fn < 4; ++fn) atomicAdd(&csum[wn * 64 + fn * 16 + lr], cs[fn]);
    __syncthreads();
    if (tid < 256)
      atomicAdd(&part[(size_t)(blockIdx.x & (CS_PARTS - 1)) * 256 + tid], csum[tid]);
  }
}

// sum the CS_PARTS partials
__global__ void colsum_p2(const float* __restrict__ part, float* __restrict__ out) {
  const int c = threadIdx.x;  // 256
  float s = 0.f;
  for (int p = 0; p < CS_PARTS; ++p) s += part[(size_t)p * 256 + c];
  out[c] = s;
}

// new_globals = relu([esum | nsum | globals] @ Wg + bg), fp32
__global__ void global_mlp(const float* __restrict__ esum, const float* __restrict__ nsum,
                           const float* __restrict__ gl, const float* __restrict__ Wg,
                           const float* __restrict__ bg, float* __restrict__ out2) {
  __shared__ float red[512];
  int g = threadIdx.x & 127;
  int kg = threadIdx.x >> 7;
  float acc = 0.f;
  for (int k = kg; k < 640; k += 4) {
    float x = (k < 256) ? esum[k] : (k < 512 ? nsum[k - 256] : gl[k - 512]);
    acc += x * Wg[(size_t)k * 128 + g];
  }
  red[threadIdx.x] = acc;
  __syncthreads();
  if (kg == 0) {
    float r = red[g] + red[128 + g] + red[256 + g] + red[384 + g] + bg[g];
    out2[g] = fmaxf(r, 0.f);
  }
}

extern "C" void kernel_launch(void* const* d_in, const int* in_sizes, int n_in,
                              void* d_out, int out_size, void* d_ws, size_t ws_size,
                              hipStream_t stream) {
  const float* nodes = (const float*)d_in[0];
  const float* edges = (const float*)d_in[1];
  const float* gl = (const float*)d_in[2];
  const int* senders = (const int*)d_in[3];
  const int* receivers = (const int*)d_in[4];
  const float* We = (const float*)d_in[5];
  const float* be = (const float*)d_in[6];
  const float* Wn = (const float*)d_in[7];
  const float* bn = (const float*)d_in[8];
  const float* Wg = (const float*)d_in[9];
  const float* bg = (const float*)d_in[10];

  float* out0 = (float*)d_out;               // new_edges [200000,256]
  float* out1 = out0 + (size_t)E_CNT * 256;  // new_nodes [50000,256]
  float* out2 = out1 + (size_t)N_CNT * 256;  // new_globals [128]

  char* ws = (char*)d_ws;
  size_t o = 0;
  int* count = (int*)(ws + o);                      o += 200704;
  float* partE = (float*)(ws + o);                  o += CS_PARTS * 256 * 4;
  float* partN = (float*)(ws + o);                  o += CS_PARTS * 256 * 4;
  size_t zeroBytes = o;  // count + partE + partN zeroed in one memset
  int* offs = (int*)(ws + o);                       o += 200704;  // N_CNT+1
  int* cursor = (int*)(ws + o);                     o += 200704;
  int* eord = (int*)(ws + o);                       o += 800000;
  unsigned short* Ps = (unsigned short*)(ws + o);   o += (size_t)N_CNT * 256 * 2;
  unsigned short* Pr = (unsigned short*)(ws + o);   o += (size_t)N_CNT * 256 * 2;
  unsigned short* Pn = (unsigned short*)(ws + o);   o += (size_t)N_CNT * 256 * 2;
  unsigned short* BpEe = (unsigned short*)(ws + o); o += 131072;
  unsigned short* BpPs = (unsigned short*)(ws + o); o += 131072;
  unsigned short* BpPr = (unsigned short*)(ws + o); o += 131072;
  unsigned short* BpNe = (unsigned short*)(ws + o); o += 131072;
  unsigned short* BpPn = (unsigned short*)(ws + o); o += 131072;
  float* ce = (float*)(ws + o);                     o += 1024;
  float* cn = (float*)(ws + o);                     o += 1024;
  float* esum = (float*)(ws + o);                   o += 1024;
  float* nsum = (float*)(ws + o);                   o += 1024;

  hipMemsetAsync(ws, 0, zeroBytes, stream);

  prep_all<<<162, 256, 0, stream>>>(We, be, Wn, bn, gl, BpEe, BpPs, BpPr, BpNe,
                                    BpPn, ce, cn);

  hist<<<(E_CNT + 255) / 256, 256, 0, stream>>>(receivers, count);
  scan_build<<<1, 1024, 0, stream>>>(count, offs, cursor);
  scatter<<<(E_CNT + 255) / 256, 256, 0, stream>>>(receivers, cursor, eord);

  // three projections in one dispatch: Ps, Pr, Pn (bf16 slot layout)
  const int nbN = (N_CNT + 63) / 64;  // 782
  gemm_core<0><<<3 * nbN, 512, 0, stream>>>(
      nodes, BpPs, BpPr, BpPn, nullptr, nullptr, nullptr, nullptr, nullptr,
      nullptr, nullptr, nullptr, Ps, Pr, Pn, nullptr, nbN, N_CNT);

  // edge: relu(edges@We_e + Ps[s] + Pr[r] + ce); nt-store; NO atomics
  gemm_core<1><<<E_CNT / 64, 512, 0, stream>>>(
      edges, BpEe, nullptr, nullptr, Ps, Pr, ce, senders, receivers, nullptr,
      nullptr, out0, nullptr, nullptr, nullptr, partE, 0, E_CNT);

  colsum_p2<<<1, 256, 0, stream>>>(partE, esum);  // == colsum(new_edges)

  // node: CSR gather-sum staging from out0; relu(agg@Wn_e + Pn[n] + cn)
  gemm_core<2><<<nbN, 512, 0, stream>>>(
      out0, BpNe, nullptr, nullptr, Pn, nullptr, cn, nullptr, nullptr, offs,
      eord, out1, nullptr, nullptr, nullptr, partN, 0, N_CNT);

  colsum_p2<<<1, 256, 0, stream>>>(partN, nsum);

  global_mlp<<<1, 512, 0, stream>>>(esum, nsum, gl, Wg, bg, out2);
}